// Round 7
// baseline (225.439 us; speedup 1.0000x reference)
//
#include <hip/hip_runtime.h>
#include <math.h>

// (B,S,D,C) = (64, 576, 768, 200)
#define Bsz  64
#define Ssz  576
#define Dsz  768
#define Csz  200
#define NKT  12         // K tiles of 64 floats (3 per wave)
#define NRB  2304       // row-blocks of 16 (= B*S/16) = grid of attn

typedef float f32x4 __attribute__((ext_vector_type(4)));
typedef long  lx2   __attribute__((ext_vector_type(2)));

// one-time: W (200x768 fp32) -> fp8 e4m3 pre-swizzled into MFMA B-fragment order.
// Record (kt,t) = 1024 B at ((kt*13+t)*1024): lane l holds 16 B = [k2=0 8B][k2=1 8B],
// bytes = Wfp8[row = t*16 + (l&15)][col = kt*64 + k2*32 + ((l>>4)>>1)*16 + ((l>>4)&1)*8 ..+8].
// Logical row 200 = ones (rowsum trick), rows 201..207 = 0.
__global__ __launch_bounds__(256) void prep_w8(const float* __restrict__ W,
                                               unsigned long long* __restrict__ Wq) {
    const int i  = blockIdx.x * 256 + threadIdx.x;   // 12*13*64*2 = 19968 8-byte halves
    const int h  = i & 1;                            // k2
    const int j  = i >> 1;                           // (kt*13+t)*64 + l
    const int l  = j & 63;
    const int r2 = j >> 6;                           // kt*13 + t
    const int t  = r2 % 13;
    const int kt = r2 / 13;
    const int q  = l >> 4, m = l & 15;
    const int row = t * 16 + m;
    const int col = kt * 64 + h * 32 + ((q >> 1) << 4) + ((q & 1) << 3);
    unsigned long long v = 0ull;
    if (row < Csz) {
        const float4 a = *(const float4*)(W + (size_t)row * Dsz + col);
        const float4 b = *(const float4*)(W + (size_t)row * Dsz + col + 4);
        unsigned int lo = __builtin_amdgcn_cvt_pk_fp8_f32(a.x, a.y, 0u, false);
        lo = __builtin_amdgcn_cvt_pk_fp8_f32(a.z, a.w, lo, true);
        unsigned int hi = __builtin_amdgcn_cvt_pk_fp8_f32(b.x, b.y, 0u, false);
        hi = __builtin_amdgcn_cvt_pk_fp8_f32(b.z, b.w, hi, true);
        v = ((unsigned long long)hi << 32) | (unsigned long long)lo;
    } else if (row == Csz) {
        v = 0x3838383838383838ull;   // fp8 e4m3 1.0 x8
    }
    Wq[i] = v;
}

// X fp32 -> fp8, pre-swizzled into A-fragment records. READ side is perfectly
// coalesced (lane i -> consecutive float4 = the D2D-copy pattern): this kernel
// is also the probe for X's raw streaming rate. Record (rblk,kt) = 1024 B at
// ((rblk*12+kt)<<10): lane l holds 16 B = [k2=0 8B][k2=1 8B] of
// Xfp8[row=rblk*16+(l&15)][col=kt*64+k2*32+(l>>4)*8 ..+8].
__global__ __launch_bounds__(256) void xq_kernel(const float* __restrict__ X,
                                                 unsigned char* __restrict__ Xq) {
    const int tid0 = blockIdx.x * 256 + threadIdx.x;
    for (int i = tid0; i < (Bsz * Ssz * Dsz / 4); i += 2048 * 256) {
        const float4 v = ((const float4*)X)[i];
        unsigned int u = __builtin_amdgcn_cvt_pk_fp8_f32(v.x, v.y, 0u, false);
        u = __builtin_amdgcn_cvt_pk_fp8_f32(v.z, v.w, u, true);
        const int row  = i / 192;                // 192 float4 per 768-col row
        const int c4   = (i - row * 192) * 4;    // col of v.x (multiple of 4)
        const int rblk = row >> 4, m = row & 15;
        const int kt   = c4 >> 6,  c6 = c4 & 63;
        const int k2   = c6 >> 5,  q = (c6 >> 3) & 3, b0 = c6 & 7;
        *(unsigned int*)(Xq + (((size_t)rblk * 12 + kt) << 10)
                            + (((q << 4) | m) << 4) + (k2 << 3) + b0) = u;
    }
}

// global classifier runs FIRST: out[b,c] = ct[b]·gw[c] + gb[c]  (exact fp32)
__global__ __launch_bounds__(256) void gc_kernel(
    const float* __restrict__ ct, const float* __restrict__ gw,
    const float* __restrict__ gb, float* __restrict__ out) {
    const int b    = blockIdx.x;
    const int wv   = threadIdx.x >> 6;
    const int lane = threadIdx.x & 63;
    const int c    = blockIdx.y * 4 + wv;
    const float* wr = gw + (size_t)c * Dsz + lane * 12;
    const float* cr = ct + (size_t)b * Dsz + lane * 12;
    float s = 0.f;
#pragma unroll
    for (int j = 0; j < 3; ++j) {
        const float4 w = *(const float4*)(wr + 4 * j);
        const float4 x = *(const float4*)(cr + 4 * j);
        s += w.x * x.x + w.y * x.y + w.z * x.z + w.w * x.w;
    }
#pragma unroll
    for (int off = 32; off > 0; off >>= 1) s += __shfl_down(s, off, 64);
    if (lane == 0) out[b * Csz + c] = s + gb[c];
}

// One K-tile worth of MFMAs: 13 W records (coalesced lx2), 7+6 split to cap
// live VGPRs. A0/A1 are the two k2-halves of the lane's A fragment.
__device__ __forceinline__ void mmkk(const long A0, const long A1,
                                     const unsigned char* wrec, f32x4 (&acc)[13]) {
    lx2 wfa[7];
#pragma unroll
    for (int t = 0; t < 7; ++t)
        wfa[t] = *(const lx2*)(wrec + (size_t)t * 1024);
    __builtin_amdgcn_s_setprio(1);
#pragma unroll
    for (int t = 0; t < 7; ++t) {
        acc[t] = __builtin_amdgcn_mfma_f32_16x16x32_fp8_fp8(A0, wfa[t][0], acc[t], 0, 0, 0);
        acc[t] = __builtin_amdgcn_mfma_f32_16x16x32_fp8_fp8(A1, wfa[t][1], acc[t], 0, 0, 0);
    }
    __builtin_amdgcn_s_setprio(0);
    lx2 wfb[6];
#pragma unroll
    for (int t = 0; t < 6; ++t)
        wfb[t] = *(const lx2*)(wrec + (size_t)(7 + t) * 1024);
    __builtin_amdgcn_s_setprio(1);
#pragma unroll
    for (int t = 0; t < 6; ++t) {
        acc[7 + t] = __builtin_amdgcn_mfma_f32_16x16x32_fp8_fp8(A0, wfb[t][0], acc[7 + t], 0, 0, 0);
        acc[7 + t] = __builtin_amdgcn_mfma_f32_16x16x32_fp8_fp8(A1, wfb[t][1], acc[7 + t], 0, 0, 0);
    }
    __builtin_amdgcn_s_setprio(0);
}

// R5 skeleton, fully-coalesced edition: block = 16 rows (grid 2304), 4 waves
// split K (3 kt each). A comes from 3x 16B/lane record loads (1 KB/instr
// contiguous — the gather is GONE); W records from global (coalesced, L2-hot).
// Split-K merge via 27 KB LDS tree; wave 0 runs the proven epilogue.
__global__ __launch_bounds__(256, 4) void attn_kernel(
    const unsigned char* __restrict__ Xq,   // swizzled A records, 27 MB
    const unsigned char* __restrict__ Wq,   // swizzled B records, 156 KB
    const float* __restrict__ attn_b,       // (C,)
    const float* __restrict__ lam,          // (1,)
    float* __restrict__ out)                // (B, C): gscore already written
{
    __shared__ float sred[2][64][53];       // 27136 B (53 = pad)

    const int tid  = threadIdx.x;
    const int lane = tid & 63;
    const int w    = tid >> 6;      // kt = 3w + {0,1,2}
    const int m    = lane & 15;
    const int q    = lane >> 4;
    const int rblk = blockIdx.x;
    const int bidx = blockIdx.x / 36;       // 36 row-blocks per batch

    // A records for this wave: 3 coalesced 16B/lane loads, issued up front
    const unsigned char* xqp = Xq + (((size_t)rblk * 12 + 3 * w) << 10) + lane * 16;
    const lx2 xf0 = *(const lx2*)(xqp);
    const lx2 xf1 = *(const lx2*)(xqp + 1024);
    const lx2 xf2 = *(const lx2*)(xqp + 2048);

    const unsigned char* wp = Wq + lane * 16;

    f32x4 acc[13];
#pragma unroll
    for (int t = 0; t < 13; ++t) acc[t] = (f32x4){0.f, 0.f, 0.f, 0.f};

    mmkk(xf0[0], xf0[1], wp + (size_t)(3 * w + 0) * 13 * 1024, acc);
    mmkk(xf1[0], xf1[1], wp + (size_t)(3 * w + 1) * 13 * 1024, acc);
    mmkk(xf2[0], xf2[1], wp + (size_t)(3 * w + 2) * 13 * 1024, acc);

    // ---- split-K merge: waves 2,3 -> LDS; 0,1 add; wave1 -> LDS; wave0 adds
    if (w >= 2) {
#pragma unroll
        for (int t = 0; t < 13; ++t) {
#pragma unroll
            for (int r = 0; r < 4; ++r) sred[w - 2][lane][t * 4 + r] = acc[t][r];
        }
    }
    __syncthreads();
    if (w < 2) {
#pragma unroll
        for (int t = 0; t < 13; ++t) {
#pragma unroll
            for (int r = 0; r < 4; ++r) acc[t][r] += sred[w][lane][t * 4 + r];
        }
    }
    __syncthreads();
    if (w == 1) {
#pragma unroll
        for (int t = 0; t < 13; ++t) {
#pragma unroll
            for (int r = 0; r < 4; ++r) sred[0][lane][t * 4 + r] = acc[t][r];
        }
    }
    __syncthreads();

    if (w == 0) {
#pragma unroll
        for (int t = 0; t < 13; ++t) {
#pragma unroll
            for (int r = 0; r < 4; ++r) acc[t][r] += sred[0][lane][t * 4 + r];
        }
        // rowsum via ones-column: tile 12, col 200 => m==8 lanes; row = q*4+r
        float rsv[4];
#pragma unroll
        for (int r = 0; r < 4; ++r) rsv[r] = __shfl(acc[12][r], (lane & 48) + 8, 64);

        const float scale = lam[0] * (1.f / ((float)Ssz * (float)Dsz));
        // epilogue: C/D col = lane&15, row = q*4+reg; reduce 16 rows, atomic add
#pragma unroll
        for (int t = 0; t < 13; ++t) {
            const int c = t * 16 + m;
            if (c < Csz) {
                const float bias = attn_b[c];
                float s = 0.f;
#pragma unroll
                for (int r = 0; r < 4; ++r)
                    s += rsv[r] / (1.f + __expf(-(acc[t][r] + bias)));
                s += __shfl_xor(s, 16, 64);
                s += __shfl_xor(s, 32, 64);
                if (q == 0) atomicAdd(&out[bidx * Csz + c], s * scale);
            }
        }
    }
}

extern "C" void kernel_launch(void* const* d_in, const int* in_sizes, int n_in,
                              void* d_out, int out_size, void* d_ws, size_t ws_size,
                              hipStream_t stream) {
    const float* X   = (const float*)d_in[0];
    const float* ct  = (const float*)d_in[1];
    const float* aw  = (const float*)d_in[2];
    const float* ab  = (const float*)d_in[3];
    const float* gw  = (const float*)d_in[4];
    const float* gb  = (const float*)d_in[5];
    const float* lam = (const float*)d_in[6];
    float* out = (float*)d_out;
    unsigned long long* Wq = (unsigned long long*)d_ws;            // 156 KB swizzled fp8 W
    unsigned char* Xq = (unsigned char*)d_ws + (1 << 20);          // 27 MB swizzled fp8 X

    prep_w8<<<(NKT * 13 * 64 * 2) / 256, 256, 0, stream>>>(aw, Wq);
    xq_kernel<<<2048, 256, 0, stream>>>(X, Xq);
    gc_kernel<<<dim3(Bsz, Csz / 4), 256, 0, stream>>>(ct, gw, gb, out);
    attn_kernel<<<NRB, 256, 0, stream>>>(Xq, (const unsigned char*)Wq, ab, lam, out);
}

// Round 8
// 207.723 us; speedup vs baseline: 1.0853x; 1.0853x over previous
//
#include <hip/hip_runtime.h>
#include <math.h>

// (B,S,D,C) = (64, 576, 768, 200)
#define Bsz  64
#define Ssz  576
#define Dsz  768
#define Csz  200
#define NKT  12         // K tiles of 64 floats (3 per wave)
#define NRB  2304       // row-blocks of 16 (= B*S/16) = grid of attn

typedef float f32x4 __attribute__((ext_vector_type(4)));
typedef long  lx2   __attribute__((ext_vector_type(2)));

// one-time: W (200x768 fp32) -> fp8 e4m3 pre-swizzled into MFMA B-fragment order.
// Record (kt,t) = 1024 B at ((kt*13+t)*1024): lane l holds 16 B = [k2=0 8B][k2=1 8B],
// bytes = Wfp8[row = t*16 + (l&15)][col = kt*64 + k2*32 + ((l>>4)>>1)*16 + ((l>>4)&1)*8 ..+8].
// Logical row 200 = ones (rowsum trick), rows 201..207 = 0.
__global__ __launch_bounds__(256) void prep_w8(const float* __restrict__ W,
                                               unsigned long long* __restrict__ Wq) {
    const int i  = blockIdx.x * 256 + threadIdx.x;   // 12*13*64*2 = 19968 8-byte halves
    const int h  = i & 1;                            // k2
    const int j  = i >> 1;                           // (kt*13+t)*64 + l
    const int l  = j & 63;
    const int r2 = j >> 6;                           // kt*13 + t
    const int t  = r2 % 13;
    const int kt = r2 / 13;
    const int q  = l >> 4, m = l & 15;
    const int row = t * 16 + m;
    const int col = kt * 64 + h * 32 + ((q >> 1) << 4) + ((q & 1) << 3);
    unsigned long long v = 0ull;
    if (row < Csz) {
        const float4 a = *(const float4*)(W + (size_t)row * Dsz + col);
        const float4 b = *(const float4*)(W + (size_t)row * Dsz + col + 4);
        unsigned int lo = __builtin_amdgcn_cvt_pk_fp8_f32(a.x, a.y, 0u, false);
        lo = __builtin_amdgcn_cvt_pk_fp8_f32(a.z, a.w, lo, true);
        unsigned int hi = __builtin_amdgcn_cvt_pk_fp8_f32(b.x, b.y, 0u, false);
        hi = __builtin_amdgcn_cvt_pk_fp8_f32(b.z, b.w, hi, true);
        v = ((unsigned long long)hi << 32) | (unsigned long long)lo;
    } else if (row == Csz) {
        v = 0x3838383838383838ull;   // fp8 e4m3 1.0 x8
    }
    Wq[i] = v;
}

// global classifier runs FIRST: out[b,c] = ct[b]·gw[c] + gb[c]  (exact fp32)
__global__ __launch_bounds__(256) void gc_kernel(
    const float* __restrict__ ct, const float* __restrict__ gw,
    const float* __restrict__ gb, float* __restrict__ out) {
    const int b    = blockIdx.x;
    const int wv   = threadIdx.x >> 6;
    const int lane = threadIdx.x & 63;
    const int c    = blockIdx.y * 4 + wv;
    const float* wr = gw + (size_t)c * Dsz + lane * 12;
    const float* cr = ct + (size_t)b * Dsz + lane * 12;
    float s = 0.f;
#pragma unroll
    for (int j = 0; j < 3; ++j) {
        const float4 w = *(const float4*)(wr + 4 * j);
        const float4 x = *(const float4*)(cr + 4 * j);
        s += w.x * x.x + w.y * x.y + w.z * x.z + w.w * x.w;
    }
#pragma unroll
    for (int off = 32; off > 0; off >>= 1) s += __shfl_down(s, off, 64);
    if (lane == 0) out[b * Csz + c] = s + gb[c];
}

__device__ __forceinline__ long cvtA(const f32x4 lo, const f32x4 hi) {
    union { long l; unsigned int u[2]; } A;
    A.u[0] = __builtin_amdgcn_cvt_pk_fp8_f32(lo.x, lo.y, 0u, false);
    A.u[0] = __builtin_amdgcn_cvt_pk_fp8_f32(lo.z, lo.w, A.u[0], true);
    A.u[1] = __builtin_amdgcn_cvt_pk_fp8_f32(hi.x, hi.y, 0u, false);
    A.u[1] = __builtin_amdgcn_cvt_pk_fp8_f32(hi.z, hi.w, A.u[1], true);
    return A.l;
}

// One K-tile worth of MFMAs: 13 W records (coalesced lx2 from global, L2-hot),
// 7+6 split to cap live VGPRs. A0/A1 are the two k2-halves of the A fragment.
__device__ __forceinline__ void mmkk(const long A0, const long A1,
                                     const unsigned char* wrec, f32x4 (&acc)[13]) {
    lx2 wfa[7];
#pragma unroll
    for (int t = 0; t < 7; ++t)
        wfa[t] = *(const lx2*)(wrec + (size_t)t * 1024);
    __builtin_amdgcn_s_setprio(1);
#pragma unroll
    for (int t = 0; t < 7; ++t) {
        acc[t] = __builtin_amdgcn_mfma_f32_16x16x32_fp8_fp8(A0, wfa[t][0], acc[t], 0, 0, 0);
        acc[t] = __builtin_amdgcn_mfma_f32_16x16x32_fp8_fp8(A1, wfa[t][1], acc[t], 0, 0, 0);
    }
    __builtin_amdgcn_s_setprio(0);
    lx2 wfb[6];
#pragma unroll
    for (int t = 0; t < 6; ++t)
        wfb[t] = *(const lx2*)(wrec + (size_t)(7 + t) * 1024);
    __builtin_amdgcn_s_setprio(1);
#pragma unroll
    for (int t = 0; t < 6; ++t) {
        acc[7 + t] = __builtin_amdgcn_mfma_f32_16x16x32_fp8_fp8(A0, wfb[t][0], acc[7 + t], 0, 0, 0);
        acc[7 + t] = __builtin_amdgcn_mfma_f32_16x16x32_fp8_fp8(A1, wfb[t][1], acc[7 + t], 0, 0, 0);
    }
    __builtin_amdgcn_s_setprio(0);
}

// Fused single-pass: block = 16 rows (grid 2304), 4 waves split K (3 kt each).
// Phase 1: X staged FULLY CONTIGUOUSLY (each wave-instr = 1 KB straight-line;
// block streams 48 KB sequential) into XOR-swizzled row-major LDS (R0-proven
// layout, conflict-free both sides). Phase 2: A from LDS + fp8 cvt, W from
// pre-swizzled global records. Phase 3: split-K merge reusing staging LDS;
// wave 0 runs the proven epilogue. 48 KB LDS -> 3 blocks/CU = 12 waves/CU.
__global__ __launch_bounds__(256, 3) void attn_kernel(
    const float* __restrict__ X,            // (B*S, D) fp32
    const unsigned char* __restrict__ Wq,   // swizzled B records, 156 KB
    const float* __restrict__ attn_b,       // (C,)
    const float* __restrict__ lam,          // (1,)
    float* __restrict__ out)                // (B, C): gscore already written
{
    __shared__ float sXf[16 * Dsz];         // 49152 B; reused as merge buffer

    const int tid  = threadIdx.x;
    const int lane = tid & 63;
    const int w    = tid >> 6;      // kt = 3w + {0,1,2}
    const int m    = lane & 15;
    const int q    = lane >> 4;
    const int rblk = blockIdx.x;
    const int bidx = blockIdx.x / 36;       // 36 row-blocks per batch

    // ---- Phase 1: stream the block's 48 KB of X (sequential), scatter to LDS.
    // f4 j -> row r = j/192, chunk cp = j%192; stored at swizzled chunk
    // (cp & ~15) | ((cp ^ r) & 15)  [XOR within each kt's 16 chunks, R0 layout]
    const float* xbase = X + (size_t)rblk * 16 * Dsz;
    f32x4 stg[12];
#pragma unroll
    for (int it = 0; it < 12; ++it)
        stg[it] = ((const f32x4*)xbase)[it * 256 + tid];
#pragma unroll
    for (int it = 0; it < 12; ++it) {
        const int j   = it * 256 + tid;
        const int r   = j / 192;
        const int cp  = j - r * 192;
        const int cps = (cp & ~15) | ((cp ^ r) & 15);
        *(f32x4*)&sXf[(r * 192 + cps) * 4] = stg[it];
    }
    __syncthreads();

    f32x4 acc[13];
#pragma unroll
    for (int t = 0; t < 13; ++t) acc[t] = (f32x4){0.f, 0.f, 0.f, 0.f};

    const unsigned char* wp = Wq + lane * 16;

    // ---- Phase 2: 3 K-tiles per wave. A-fragment: lane (q,m) owns row m,
    // floats kt*64 + k2*32 + q*8 .. +8  ->  chunks cp0 = kt*16 + k2*8 + q*2, +1
#pragma unroll
    for (int kk = 0; kk < 3; ++kk) {
        const int kt = 3 * w + kk;
        long A01[2];
#pragma unroll
        for (int k2 = 0; k2 < 2; ++k2) {
            const int cp0 = kt * 16 + k2 * 8 + q * 2;
            const int cl  = (cp0 & ~15) | ((cp0 ^ m) & 15);
            const int ch  = ((cp0 + 1) & ~15) | (((cp0 + 1) ^ m) & 15);
            const f32x4 alo = *(const f32x4*)&sXf[(m * 192 + cl) * 4];
            const f32x4 ahi = *(const f32x4*)&sXf[(m * 192 + ch) * 4];
            A01[k2] = cvtA(alo, ahi);
        }
        mmkk(A01[0], A01[1], wp + (size_t)kt * 13 * 1024, acc);
    }

    // ---- Phase 3: split-K merge (reuse sXf; pad stride 53)
    float* sred = sXf;
    __syncthreads();                        // all A-reads done before overwrite
    if (w >= 2) {
#pragma unroll
        for (int t = 0; t < 13; ++t) {
#pragma unroll
            for (int r = 0; r < 4; ++r)
                sred[(w - 2) * 3392 + lane * 53 + t * 4 + r] = acc[t][r];
        }
    }
    __syncthreads();
    if (w < 2) {
#pragma unroll
        for (int t = 0; t < 13; ++t) {
#pragma unroll
            for (int r = 0; r < 4; ++r)
                acc[t][r] += sred[w * 3392 + lane * 53 + t * 4 + r];
        }
    }
    __syncthreads();
    if (w == 1) {
#pragma unroll
        for (int t = 0; t < 13; ++t) {
#pragma unroll
            for (int r = 0; r < 4; ++r)
                sred[lane * 53 + t * 4 + r] = acc[t][r];
        }
    }
    __syncthreads();

    if (w == 0) {
#pragma unroll
        for (int t = 0; t < 13; ++t) {
#pragma unroll
            for (int r = 0; r < 4; ++r)
                acc[t][r] += sred[lane * 53 + t * 4 + r];
        }
        // rowsum via ones-column: tile 12, col 200 => m==8 lanes; row = q*4+r
        float rsv[4];
#pragma unroll
        for (int r = 0; r < 4; ++r) rsv[r] = __shfl(acc[12][r], (lane & 48) + 8, 64);

        const float scale = lam[0] * (1.f / ((float)Ssz * (float)Dsz));
        // epilogue: C/D col = lane&15, row = q*4+reg; reduce 16 rows, atomic add
#pragma unroll
        for (int t = 0; t < 13; ++t) {
            const int c = t * 16 + m;
            if (c < Csz) {
                const float bias = attn_b[c];
                float s = 0.f;
#pragma unroll
                for (int r = 0; r < 4; ++r)
                    s += rsv[r] / (1.f + __expf(-(acc[t][r] + bias)));
                s += __shfl_xor(s, 16, 64);
                s += __shfl_xor(s, 32, 64);
                if (q == 0) atomicAdd(&out[bidx * Csz + c], s * scale);
            }
        }
    }
}

extern "C" void kernel_launch(void* const* d_in, const int* in_sizes, int n_in,
                              void* d_out, int out_size, void* d_ws, size_t ws_size,
                              hipStream_t stream) {
    const float* X   = (const float*)d_in[0];
    const float* ct  = (const float*)d_in[1];
    const float* aw  = (const float*)d_in[2];
    const float* ab  = (const float*)d_in[3];
    const float* gw  = (const float*)d_in[4];
    const float* gb  = (const float*)d_in[5];
    const float* lam = (const float*)d_in[6];
    float* out = (float*)d_out;
    unsigned long long* Wq = (unsigned long long*)d_ws;   // 12*13*1024 = 156 KB swizzled fp8

    prep_w8<<<(NKT * 13 * 64 * 2) / 256, 256, 0, stream>>>(aw, Wq);
    gc_kernel<<<dim3(Bsz, Csz / 4), 256, 0, stream>>>(ct, gw, gb, out);
    attn_kernel<<<NRB, 256, 0, stream>>>(X, (const unsigned char*)Wq, ab, lam, out);
}